// Round 1
// baseline (382.753 us; speedup 1.0000x reference)
//
#include <hip/hip_runtime.h>

typedef unsigned short ushort_t;
typedef __attribute__((ext_vector_type(8))) __bf16 bf16x8;
typedef __attribute__((ext_vector_type(4))) float f32x4;
typedef __attribute__((ext_vector_type(4))) float float4v;
typedef __attribute__((ext_vector_type(8))) unsigned short ushort8v;
typedef __attribute__((ext_vector_type(4))) unsigned short ushort4v;

#define T_LEN 2048
#define D_DIM 1024
#define NHEAD 16
#define HDIM 64
#define BH 64                    // B * H
#define MROWS 8192               // B * T
#define PERQKV ((size_t)BH * T_LEN * HDIM)   // 8388608 elems

__device__ __forceinline__ ushort_t f2bf(float f) {
  unsigned u = __builtin_bit_cast(unsigned, f);
  u = (u + 0x7FFFu + ((u >> 16) & 1u)) >> 16;
  return (ushort_t)u;
}

__device__ __forceinline__ void load_lds16(const ushort_t* g, ushort_t* l) {
  __builtin_amdgcn_global_load_lds((const __attribute__((address_space(1))) void*)g,
                                   (__attribute__((address_space(3))) void*)l, 16, 0, 0);
}

// ---------------- convert x (f32 -> bf16), 4 elems/thread ----------------
__global__ __launch_bounds__(256) void k_cvt_x(const float* __restrict__ x,
                                               ushort_t* __restrict__ xb) {
  int i = blockIdx.x * 256 + threadIdx.x;
  float4v v = ((const float4v*)x)[i];
  ushort4v o;
  o[0] = f2bf(v[0]); o[1] = f2bf(v[1]); o[2] = f2bf(v[2]); o[3] = f2bf(v[3]);
  ((ushort4v*)xb)[i] = o;
}

// ------------- transpose + convert: W[R][C] f32 -> Wt[C][R] bf16 -------------
__global__ __launch_bounds__(256) void k_transpose(const float* __restrict__ W,
                                                   ushort_t* __restrict__ Wt,
                                                   int R, int C) {
  __shared__ ushort_t tile[32][33];
  int tx = threadIdx.x & 31, ty = threadIdx.x >> 5;
  int r0 = blockIdx.y << 5, c0 = blockIdx.x << 5;
#pragma unroll
  for (int i = 0; i < 4; ++i) {
    int r = ty + i * 8;
    tile[r][tx] = f2bf(W[(size_t)(r0 + r) * C + c0 + tx]);
  }
  __syncthreads();
#pragma unroll
  for (int i = 0; i < 4; ++i) {
    int r = ty + i * 8;
    Wt[(size_t)(c0 + r) * R + r0 + tx] = tile[tx][r];
  }
}

// ---------------- GEMM: C[M][N] = A[M][K] * Bt[N][K]^T, bf16 MFMA ----------------
// 128x128 tile, BK=32, 256 threads = 4 waves (2x2), per-wave 64x64 = 4x4 frags.
// EPI 0: scatter to Q/K/V per-head layout (scale Q by 0.125). EPI 1: f32 out.
template <int N, int K, int EPI>
__global__ __launch_bounds__(256) void k_gemm(const ushort_t* __restrict__ A,
                                              const ushort_t* __restrict__ Bt,
                                              ushort_t* __restrict__ O16,
                                              float* __restrict__ O32) {
  __shared__ __align__(16) ushort_t Atile[128 * 32];
  __shared__ __align__(16) ushort_t Btile[128 * 32];
  const int tid = threadIdx.x;
  const int lane = tid & 63, w = tid >> 6;
  const int g = lane >> 4, c = lane & 15;
  const int wm = w >> 1, wn = w & 1;
  const int m0 = blockIdx.y * 128, n0 = blockIdx.x * 128;

  f32x4 acc[4][4];
#pragma unroll
  for (int i = 0; i < 4; ++i)
#pragma unroll
    for (int j = 0; j < 4; ++j) acc[i][j] = (f32x4){0.f, 0.f, 0.f, 0.f};

  for (int k0 = 0; k0 < K; k0 += 32) {
    __syncthreads();
#pragma unroll
    for (int r = 0; r < 2; ++r) {
      int flat = r * 256 + tid;
      int row = flat >> 2, slot = flat & 3;
      int gsl = slot ^ (row & 3);                 // source-swizzle (rule #21)
      load_lds16(A + (size_t)(m0 + row) * K + k0 + gsl * 8,
                 &Atile[(r * 256 + w * 64) * 8]);
      load_lds16(Bt + (size_t)(n0 + row) * K + k0 + gsl * 8,
                 &Btile[(r * 256 + w * 64) * 8]);
    }
    __syncthreads();

    bf16x8 af[4], bfr[4];
#pragma unroll
    for (int mi = 0; mi < 4; ++mi) {
      int row = wm * 64 + mi * 16 + c;
      int sl = g ^ (row & 3);                     // matching read swizzle
      af[mi] = *(const bf16x8*)&Atile[row * 32 + sl * 8];
    }
#pragma unroll
    for (int ni = 0; ni < 4; ++ni) {
      int row = wn * 64 + ni * 16 + c;
      int sl = g ^ (row & 3);
      bfr[ni] = *(const bf16x8*)&Btile[row * 32 + sl * 8];
    }
#pragma unroll
    for (int mi = 0; mi < 4; ++mi)
#pragma unroll
      for (int ni = 0; ni < 4; ++ni)
        acc[mi][ni] = __builtin_amdgcn_mfma_f32_16x16x32_bf16(af[mi], bfr[ni],
                                                              acc[mi][ni], 0, 0, 0);
  }

#pragma unroll
  for (int mi = 0; mi < 4; ++mi)
#pragma unroll
    for (int ni = 0; ni < 4; ++ni) {
      int n = n0 + wn * 64 + ni * 16 + c;
#pragma unroll
      for (int j = 0; j < 4; ++j) {
        int m = m0 + wm * 64 + mi * 16 + g * 4 + j;
        float v = acc[mi][ni][j];
        if constexpr (EPI == 0) {
          int which = n >> 10, hn = n & 1023;
          int h = hn >> 6, d = hn & 63;
          int b = m >> 11, t = m & 2047;
          if (which == 0) v *= 0.125f;            // fold 1/sqrt(HD) into Q
          O16[(size_t)which * PERQKV +
              (((size_t)(b * NHEAD + h) * T_LEN + t) * HDIM + d)] = f2bf(v);
        } else {
          O32[(size_t)m * N + n] = v;
        }
      }
    }
}

// ---------------- flash attention: QBLK=64 (4 waves x 16 rows), KVBLK=64 ----------------
__global__ __launch_bounds__(256) void k_attn(const ushort_t* __restrict__ Q,
                                              const ushort_t* __restrict__ Kv,
                                              const ushort_t* __restrict__ Vv,
                                              ushort_t* __restrict__ Y) {
  __shared__ __align__(16) ushort_t Kt[64 * 64];      // slot-swizzled
  __shared__ __align__(16) ushort_t Vt[64 * 68];      // stride 68
  __shared__ __align__(16) ushort_t Pl[4][16 * 72];   // per-wave P, stride 72

  const int qt = blockIdx.x;   // q tile 0..31
  const int bh = blockIdx.y;   // 0..63
  const int tid = threadIdx.x, lane = tid & 63, w = tid >> 6;
  const int g = lane >> 4, c = lane & 15;
  const size_t base = (size_t)bh * (T_LEN * HDIM);

  // Q A-fragments in registers (already scaled by 0.125)
  const int qrow_frag = qt * 64 + w * 16 + c;
  bf16x8 qa[2];
#pragma unroll
  for (int ds = 0; ds < 2; ++ds)
    qa[ds] = *(const bf16x8*)(Q + base + (size_t)qrow_frag * HDIM + ds * 32 + g * 8);

  f32x4 o[4];
#pragma unroll
  for (int b = 0; b < 4; ++b) o[b] = (f32x4){0.f, 0.f, 0.f, 0.f};
  float mrun[4], lrun[4];
#pragma unroll
  for (int j = 0; j < 4; ++j) { mrun[j] = -__builtin_inff(); lrun[j] = 0.f; }

  const int qr_acc_base = qt * 64 + w * 16 + g * 4;

  for (int kt = 0; kt <= qt; ++kt) {
    __syncthreads();
    // stage K tile (swizzled source -> linear LDS)
#pragma unroll
    for (int r = 0; r < 2; ++r) {
      int flat = r * 256 + tid;
      int row = flat >> 3, sl = flat & 7;
      int gs = sl ^ (row & 7);
      load_lds16(Kv + base + (size_t)(kt * 64 + row) * HDIM + gs * 8,
                 &Kt[(r * 256 + w * 64) * 8]);
    }
    // stage V tile (reg -> LDS, stride 68)
#pragma unroll
    for (int r = 0; r < 2; ++r) {
      int flat = r * 256 + tid;
      int vr = flat >> 3, c0 = (flat & 7) * 8;
      ushort8v vv = *(const ushort8v*)(Vv + base + (size_t)(kt * 64 + vr) * HDIM + c0);
      ushort4v lo = {vv[0], vv[1], vv[2], vv[3]};
      ushort4v hi = {vv[4], vv[5], vv[6], vv[7]};
      *(ushort4v*)&Vt[vr * 68 + c0] = lo;
      *(ushort4v*)&Vt[vr * 68 + c0 + 4] = hi;
    }
    __syncthreads();

    // S = Q K^T (per wave: 16 q-rows x 64 k-cols)
    f32x4 s[4];
#pragma unroll
    for (int kf = 0; kf < 4; ++kf) {
      f32x4 z = (f32x4){0.f, 0.f, 0.f, 0.f};
#pragma unroll
      for (int ds = 0; ds < 2; ++ds) {
        int krow = kf * 16 + c;
        int sl = (ds * 4 + g) ^ (krow & 7);
        bf16x8 kb = *(const bf16x8*)&Kt[krow * 64 + sl * 8];
        z = __builtin_amdgcn_mfma_f32_16x16x32_bf16(qa[ds], kb, z, 0, 0, 0);
      }
      s[kf] = z;
    }

    if (kt == qt) {  // diagonal tile causal mask
#pragma unroll
      for (int kf = 0; kf < 4; ++kf)
#pragma unroll
        for (int j = 0; j < 4; ++j) {
          int kc = kt * 64 + kf * 16 + c;
          if (kc > qr_acc_base + j) s[kf][j] = -1e30f;
        }
    }

    // online softmax (wave-parallel; rows live in 16-lane groups)
    float scale_o[4];
#pragma unroll
    for (int j = 0; j < 4; ++j) {
      float mx = fmaxf(fmaxf(s[0][j], s[1][j]), fmaxf(s[2][j], s[3][j]));
      mx = fmaxf(mx, __shfl_xor(mx, 1));
      mx = fmaxf(mx, __shfl_xor(mx, 2));
      mx = fmaxf(mx, __shfl_xor(mx, 4));
      mx = fmaxf(mx, __shfl_xor(mx, 8));
      float mnew = fmaxf(mrun[j], mx);
      float sc = __expf(mrun[j] - mnew);
      float rs = 0.f;
#pragma unroll
      for (int kf = 0; kf < 4; ++kf) {
        float p = __expf(s[kf][j] - mnew);
        s[kf][j] = p; rs += p;
      }
      rs += __shfl_xor(rs, 1); rs += __shfl_xor(rs, 2);
      rs += __shfl_xor(rs, 4); rs += __shfl_xor(rs, 8);
      lrun[j] = lrun[j] * sc + rs;
      mrun[j] = mnew;
      scale_o[j] = sc;
    }
#pragma unroll
    for (int b = 0; b < 4; ++b)
#pragma unroll
      for (int j = 0; j < 4; ++j) o[b][j] *= scale_o[j];

    // P -> per-wave LDS (D-layout scatter), then A-frag reads
#pragma unroll
    for (int kf = 0; kf < 4; ++kf)
#pragma unroll
      for (int j = 0; j < 4; ++j)
        Pl[w][(g * 4 + j) * 72 + kf * 16 + c] = f2bf(s[kf][j]);

    asm volatile("s_waitcnt lgkmcnt(0)" ::: "memory");

    // O += P V
#pragma unroll
    for (int ks = 0; ks < 2; ++ks) {
      bf16x8 ap = *(const bf16x8*)&Pl[w][c * 72 + ks * 32 + g * 8];
#pragma unroll
      for (int b = 0; b < 4; ++b) {
        ushort8v vv;
#pragma unroll
        for (int e = 0; e < 8; ++e)
          vv[e] = Vt[(ks * 32 + g * 8 + e) * 68 + b * 16 + c];
        o[b] = __builtin_amdgcn_mfma_f32_16x16x32_bf16(ap, __builtin_bit_cast(bf16x8, vv),
                                                       o[b], 0, 0, 0);
      }
    }
  }

  // finalize: y[b][t][h*64+d]
  const int b_ = bh >> 4, h_ = bh & 15;
#pragma unroll
  for (int bb = 0; bb < 4; ++bb)
#pragma unroll
    for (int j = 0; j < 4; ++j) {
      int qr = qr_acc_base + j;
      float val = o[bb][j] / lrun[j];
      size_t m = (size_t)b_ * T_LEN + qr;
      Y[m * D_DIM + h_ * HDIM + bb * 16 + c] = f2bf(val);
    }
}

extern "C" void kernel_launch(void* const* d_in, const int* in_sizes, int n_in,
                              void* d_out, int out_size, void* d_ws, size_t ws_size,
                              hipStream_t stream) {
  const float* x     = (const float*)d_in[0];
  const float* Wqkv  = (const float*)d_in[1];
  const float* Wproj = (const float*)d_in[2];
  float* out = (float*)d_out;
  ushort_t* ws = (ushort_t*)d_ws;

  ushort_t* Xb  = ws;
  ushort_t* WqT = Xb  + (size_t)MROWS * D_DIM;        // 8192*1024
  ushort_t* WpT = WqT + (size_t)3 * D_DIM * D_DIM;    // 3072*1024
  ushort_t* Qb  = WpT + (size_t)D_DIM * D_DIM;        // 1024*1024
  ushort_t* Kb  = Qb + PERQKV;
  ushort_t* Vb  = Kb + PERQKV;
  ushort_t* Yb  = Vb + PERQKV;

  k_cvt_x<<<(MROWS * D_DIM / 4) / 256, 256, 0, stream>>>(x, Xb);
  k_transpose<<<dim3(3 * D_DIM / 32, D_DIM / 32), 256, 0, stream>>>(Wqkv, WqT, D_DIM, 3 * D_DIM);
  k_transpose<<<dim3(D_DIM / 32, D_DIM / 32), 256, 0, stream>>>(Wproj, WpT, D_DIM, D_DIM);
  k_gemm<3 * D_DIM, D_DIM, 0><<<dim3(3 * D_DIM / 128, MROWS / 128), 256, 0, stream>>>(Xb, WqT, Qb, nullptr);
  k_attn<<<dim3(T_LEN / 64, BH), 256, 0, stream>>>(Qb, Kb, Vb, Yb);
  k_gemm<D_DIM, D_DIM, 1><<<dim3(D_DIM / 128, MROWS / 128), 256, 0, stream>>>(Yb, WpT, nullptr, out);
}

// Round 2
// 351.892 us; speedup vs baseline: 1.0877x; 1.0877x over previous
//
#include <hip/hip_runtime.h>

typedef unsigned short ushort_t;
typedef __attribute__((ext_vector_type(8))) __bf16 bf16x8;
typedef __attribute__((ext_vector_type(4))) float f32x4;
typedef __attribute__((ext_vector_type(4))) float float4v;
typedef __attribute__((ext_vector_type(8))) unsigned short ushort8v;
typedef __attribute__((ext_vector_type(4))) unsigned short ushort4v;

#define T_LEN 2048
#define D_DIM 1024
#define NHEAD 16
#define HDIM 64
#define BH 64                    // B * H
#define MROWS 8192               // B * T
#define PERQKV ((size_t)BH * T_LEN * HDIM)   // 8388608 elems

__device__ __forceinline__ ushort_t f2bf(float f) {
  unsigned u = __builtin_bit_cast(unsigned, f);
  u = (u + 0x7FFFu + ((u >> 16) & 1u)) >> 16;
  return (ushort_t)u;
}

__device__ __forceinline__ void load_lds16(const ushort_t* g, ushort_t* l) {
  __builtin_amdgcn_global_load_lds((const __attribute__((address_space(1))) void*)g,
                                   (__attribute__((address_space(3))) void*)l, 16, 0, 0);
}

// ---------------- convert x (f32 -> bf16), 4 elems/thread ----------------
__global__ __launch_bounds__(256) void k_cvt_x(const float* __restrict__ x,
                                               ushort_t* __restrict__ xb) {
  int i = blockIdx.x * 256 + threadIdx.x;
  float4v v = ((const float4v*)x)[i];
  ushort4v o;
  o[0] = f2bf(v[0]); o[1] = f2bf(v[1]); o[2] = f2bf(v[2]); o[3] = f2bf(v[3]);
  ((ushort4v*)xb)[i] = o;
}

// ------------- transpose + convert: W[R][C] f32 -> Wt[C][R] bf16 -------------
__global__ __launch_bounds__(256) void k_transpose(const float* __restrict__ W,
                                                   ushort_t* __restrict__ Wt,
                                                   int R, int C) {
  __shared__ ushort_t tile[32][33];
  int tx = threadIdx.x & 31, ty = threadIdx.x >> 5;
  int r0 = blockIdx.y << 5, c0 = blockIdx.x << 5;
#pragma unroll
  for (int i = 0; i < 4; ++i) {
    int r = ty + i * 8;
    tile[r][tx] = f2bf(W[(size_t)(r0 + r) * C + c0 + tx]);
  }
  __syncthreads();
#pragma unroll
  for (int i = 0; i < 4; ++i) {
    int r = ty + i * 8;
    Wt[(size_t)(c0 + r) * R + r0 + tx] = tile[tx][r];
  }
}

// ---------------- GEMM: C[M][N] = A[M][K] * Bt[N][K]^T, bf16 MFMA ----------------
// 128x128 tile, BK=32, 256 threads = 4 waves (2x2), per-wave 64x64 = 4x4 frags.
// EPI 0: scatter to Q/K/V per-head layout (scale Q by 0.125). EPI 1: f32 out.
template <int N, int K, int EPI>
__global__ __launch_bounds__(256) void k_gemm(const ushort_t* __restrict__ A,
                                              const ushort_t* __restrict__ Bt,
                                              ushort_t* __restrict__ O16,
                                              float* __restrict__ O32) {
  __shared__ __align__(16) ushort_t Atile[128 * 32];
  __shared__ __align__(16) ushort_t Btile[128 * 32];
  const int tid = threadIdx.x;
  const int lane = tid & 63, w = tid >> 6;
  const int g = lane >> 4, c = lane & 15;
  const int wm = w >> 1, wn = w & 1;
  const int m0 = blockIdx.y * 128, n0 = blockIdx.x * 128;

  f32x4 acc[4][4];
#pragma unroll
  for (int i = 0; i < 4; ++i)
#pragma unroll
    for (int j = 0; j < 4; ++j) acc[i][j] = (f32x4){0.f, 0.f, 0.f, 0.f};

  for (int k0 = 0; k0 < K; k0 += 32) {
    __syncthreads();
#pragma unroll
    for (int r = 0; r < 2; ++r) {
      int flat = r * 256 + tid;
      int row = flat >> 2, slot = flat & 3;
      int gsl = slot ^ (row & 3);                 // source-swizzle (rule #21)
      load_lds16(A + (size_t)(m0 + row) * K + k0 + gsl * 8,
                 &Atile[(r * 256 + w * 64) * 8]);
      load_lds16(Bt + (size_t)(n0 + row) * K + k0 + gsl * 8,
                 &Btile[(r * 256 + w * 64) * 8]);
    }
    __syncthreads();

    bf16x8 af[4], bfr[4];
#pragma unroll
    for (int mi = 0; mi < 4; ++mi) {
      int row = wm * 64 + mi * 16 + c;
      int sl = g ^ (row & 3);                     // matching read swizzle
      af[mi] = *(const bf16x8*)&Atile[row * 32 + sl * 8];
    }
#pragma unroll
    for (int ni = 0; ni < 4; ++ni) {
      int row = wn * 64 + ni * 16 + c;
      int sl = g ^ (row & 3);
      bfr[ni] = *(const bf16x8*)&Btile[row * 32 + sl * 8];
    }
#pragma unroll
    for (int mi = 0; mi < 4; ++mi)
#pragma unroll
      for (int ni = 0; ni < 4; ++ni)
        acc[mi][ni] = __builtin_amdgcn_mfma_f32_16x16x32_bf16(af[mi], bfr[ni],
                                                              acc[mi][ni], 0, 0, 0);
  }

#pragma unroll
  for (int mi = 0; mi < 4; ++mi)
#pragma unroll
    for (int ni = 0; ni < 4; ++ni) {
      int n = n0 + wn * 64 + ni * 16 + c;
#pragma unroll
      for (int j = 0; j < 4; ++j) {
        int m = m0 + wm * 64 + mi * 16 + g * 4 + j;
        float v = acc[mi][ni][j];
        if constexpr (EPI == 0) {
          int which = n >> 10, hn = n & 1023;
          int h = hn >> 6, d = hn & 63;
          int b = m >> 11, t = m & 2047;
          if (which == 0) v *= 0.125f;            // fold 1/sqrt(HD) into Q
          O16[(size_t)which * PERQKV +
              (((size_t)(b * NHEAD + h) * T_LEN + t) * HDIM + d)] = f2bf(v);
        } else {
          O32[(size_t)m * N + n] = v;
        }
      }
    }
}

// ---------------- flash attention: QBLK=64 (4 waves x 16 rows), KVBLK=64 ----------------
// V is transposed during staging: VtT[d][k] (stride 72 u16, rows 16B-aligned)
// so each PV B-fragment is one conflict-free ds_read_b128.
__global__ __launch_bounds__(256) void k_attn(const ushort_t* __restrict__ Q,
                                              const ushort_t* __restrict__ Kv,
                                              const ushort_t* __restrict__ Vv,
                                              ushort_t* __restrict__ Y) {
  __shared__ __align__(16) ushort_t Kt[64 * 64];      // slot-swizzled linear
  __shared__ __align__(16) ushort_t VtT[64 * 72];     // [d][k], stride 72
  __shared__ __align__(16) ushort_t Pl[4][16 * 72];   // per-wave P, stride 72

  const int qt = (int)gridDim.x - 1 - (int)blockIdx.x;  // big tiles first
  const int bh = blockIdx.y;   // 0..63
  const int tid = threadIdx.x, lane = tid & 63, w = tid >> 6;
  const int g = lane >> 4, c = lane & 15;
  const size_t base = (size_t)bh * (T_LEN * HDIM);

  // V staging decomposition: 2 kv-rows x 8 d-cols per thread
  const int kpair = tid & 31;          // -> rows 2*kpair, 2*kpair+1
  const int vk0 = 2 * kpair;
  const int vd0 = (tid >> 5) * 8;      // d-chunk

  // Q A-fragments in registers (already scaled by 0.125)
  const int qrow_frag = qt * 64 + w * 16 + c;
  bf16x8 qa[2];
#pragma unroll
  for (int ds = 0; ds < 2; ++ds)
    qa[ds] = *(const bf16x8*)(Q + base + (size_t)qrow_frag * HDIM + ds * 32 + g * 8);

  f32x4 o[4];
#pragma unroll
  for (int b = 0; b < 4; ++b) o[b] = (f32x4){0.f, 0.f, 0.f, 0.f};
  float mrun[4], lrun[4];
#pragma unroll
  for (int j = 0; j < 4; ++j) { mrun[j] = -__builtin_inff(); lrun[j] = 0.f; }

  const int qr_acc_base = qt * 64 + w * 16 + g * 4;

  for (int kt = 0; kt <= qt; ++kt) {
    // --- V global loads issued BEFORE the barrier (latency hides under
    // other waves' prior compute); writes happen after the barrier.
    ushort8v v0 = *(const ushort8v*)(Vv + base + (size_t)(kt * 64 + vk0) * HDIM + vd0);
    ushort8v v1 = *(const ushort8v*)(Vv + base + (size_t)(kt * 64 + vk0 + 1) * HDIM + vd0);

    __syncthreads();
    // stage K tile (swizzled source -> linear LDS)
#pragma unroll
    for (int r = 0; r < 2; ++r) {
      int flat = r * 256 + tid;
      int row = flat >> 3, sl = flat & 7;
      int gs = sl ^ (row & 7);
      load_lds16(Kv + base + (size_t)(kt * 64 + row) * HDIM + gs * 8,
                 &Kt[(r * 256 + w * 64) * 8]);
    }
    // transpose-stage V: VtT[d][k], packed u32 writes (2 k per write)
#pragma unroll
    for (int e = 0; e < 8; ++e) {
      unsigned pv = (unsigned)v0[e] | ((unsigned)v1[e] << 16);
      *(unsigned*)&VtT[(vd0 + e) * 72 + vk0] = pv;
    }
    __syncthreads();

    // S = Q K^T (per wave: 16 q-rows x 64 k-cols)
    f32x4 s[4];
#pragma unroll
    for (int kf = 0; kf < 4; ++kf) {
      f32x4 z = (f32x4){0.f, 0.f, 0.f, 0.f};
#pragma unroll
      for (int ds = 0; ds < 2; ++ds) {
        int krow = kf * 16 + c;
        int sl = (ds * 4 + g) ^ (krow & 7);
        bf16x8 kb = *(const bf16x8*)&Kt[krow * 64 + sl * 8];
        z = __builtin_amdgcn_mfma_f32_16x16x32_bf16(qa[ds], kb, z, 0, 0, 0);
      }
      s[kf] = z;
    }

    if (kt == qt) {  // diagonal tile causal mask
#pragma unroll
      for (int kf = 0; kf < 4; ++kf)
#pragma unroll
        for (int j = 0; j < 4; ++j) {
          int kc = kt * 64 + kf * 16 + c;
          if (kc > qr_acc_base + j) s[kf][j] = -1e30f;
        }
    }

    // online softmax (wave-parallel; rows live in 16-lane groups)
    float scale_o[4];
#pragma unroll
    for (int j = 0; j < 4; ++j) {
      float mx = fmaxf(fmaxf(s[0][j], s[1][j]), fmaxf(s[2][j], s[3][j]));
      mx = fmaxf(mx, __shfl_xor(mx, 1));
      mx = fmaxf(mx, __shfl_xor(mx, 2));
      mx = fmaxf(mx, __shfl_xor(mx, 4));
      mx = fmaxf(mx, __shfl_xor(mx, 8));
      float mnew = fmaxf(mrun[j], mx);
      float sc = __expf(mrun[j] - mnew);
      float rs = 0.f;
#pragma unroll
      for (int kf = 0; kf < 4; ++kf) {
        float p = __expf(s[kf][j] - mnew);
        s[kf][j] = p; rs += p;
      }
      rs += __shfl_xor(rs, 1); rs += __shfl_xor(rs, 2);
      rs += __shfl_xor(rs, 4); rs += __shfl_xor(rs, 8);
      lrun[j] = lrun[j] * sc + rs;
      mrun[j] = mnew;
      scale_o[j] = sc;
    }
#pragma unroll
    for (int b = 0; b < 4; ++b)
#pragma unroll
      for (int j = 0; j < 4; ++j) o[b][j] *= scale_o[j];

    // P -> per-wave LDS (D-layout scatter), then A-frag reads
#pragma unroll
    for (int kf = 0; kf < 4; ++kf)
#pragma unroll
      for (int j = 0; j < 4; ++j)
        Pl[w][(g * 4 + j) * 72 + kf * 16 + c] = f2bf(s[kf][j]);

    asm volatile("s_waitcnt lgkmcnt(0)" ::: "memory");

    // O += P V : B-fragments are b128 reads from transposed V
#pragma unroll
    for (int ks = 0; ks < 2; ++ks) {
      bf16x8 ap = *(const bf16x8*)&Pl[w][c * 72 + ks * 32 + g * 8];
#pragma unroll
      for (int b = 0; b < 4; ++b) {
        bf16x8 vb = *(const bf16x8*)&VtT[(b * 16 + c) * 72 + ks * 32 + g * 8];
        o[b] = __builtin_amdgcn_mfma_f32_16x16x32_bf16(ap, vb, o[b], 0, 0, 0);
      }
    }
  }

  // finalize: y[b][t][h*64+d]
  const int b_ = bh >> 4, h_ = bh & 15;
#pragma unroll
  for (int bb = 0; bb < 4; ++bb)
#pragma unroll
    for (int j = 0; j < 4; ++j) {
      int qr = qr_acc_base + j;
      float val = o[bb][j] / lrun[j];
      size_t m = (size_t)b_ * T_LEN + qr;
      Y[m * D_DIM + h_ * HDIM + bb * 16 + c] = f2bf(val);
    }
}

extern "C" void kernel_launch(void* const* d_in, const int* in_sizes, int n_in,
                              void* d_out, int out_size, void* d_ws, size_t ws_size,
                              hipStream_t stream) {
  const float* x     = (const float*)d_in[0];
  const float* Wqkv  = (const float*)d_in[1];
  const float* Wproj = (const float*)d_in[2];
  float* out = (float*)d_out;
  ushort_t* ws = (ushort_t*)d_ws;

  ushort_t* Xb  = ws;
  ushort_t* WqT = Xb  + (size_t)MROWS * D_DIM;        // 8192*1024
  ushort_t* WpT = WqT + (size_t)3 * D_DIM * D_DIM;    // 3072*1024
  ushort_t* Qb  = WpT + (size_t)D_DIM * D_DIM;        // 1024*1024
  ushort_t* Kb  = Qb + PERQKV;
  ushort_t* Vb  = Kb + PERQKV;
  ushort_t* Yb  = Vb + PERQKV;

  k_cvt_x<<<(MROWS * D_DIM / 4) / 256, 256, 0, stream>>>(x, Xb);
  k_transpose<<<dim3(3 * D_DIM / 32, D_DIM / 32), 256, 0, stream>>>(Wqkv, WqT, D_DIM, 3 * D_DIM);
  k_transpose<<<dim3(D_DIM / 32, D_DIM / 32), 256, 0, stream>>>(Wproj, WpT, D_DIM, D_DIM);
  k_gemm<3 * D_DIM, D_DIM, 0><<<dim3(3 * D_DIM / 128, MROWS / 128), 256, 0, stream>>>(Xb, WqT, Qb, nullptr);
  k_attn<<<dim3(T_LEN / 64, BH), 256, 0, stream>>>(Qb, Kb, Vb, Yb);
  k_gemm<D_DIM, D_DIM, 1><<<dim3(D_DIM / 128, MROWS / 128), 256, 0, stream>>>(Yb, WpT, nullptr, out);
}

// Round 3
// 236.689 us; speedup vs baseline: 1.6171x; 1.4867x over previous
//
#include <hip/hip_runtime.h>

typedef unsigned short ushort_t;
typedef __attribute__((ext_vector_type(8))) __bf16 bf16x8;
typedef __attribute__((ext_vector_type(4))) float f32x4;
typedef __attribute__((ext_vector_type(4))) float float4v;
typedef __attribute__((ext_vector_type(8))) unsigned short ushort8v;
typedef __attribute__((ext_vector_type(4))) unsigned short ushort4v;

#define T_LEN 2048
#define D_DIM 1024
#define NHEAD 16
#define HDIM 64
#define BH 64                    // B * H
#define MROWS 8192               // B * T
#define PERQKV ((size_t)BH * T_LEN * HDIM)   // 8388608 elems

__device__ __forceinline__ ushort_t f2bf(float f) {
  unsigned u = __builtin_bit_cast(unsigned, f);
  u = (u + 0x7FFFu + ((u >> 16) & 1u)) >> 16;
  return (ushort_t)u;
}

__device__ __forceinline__ void load_lds16(const ushort_t* g, ushort_t* l) {
  __builtin_amdgcn_global_load_lds((const __attribute__((address_space(1))) void*)g,
                                   (__attribute__((address_space(3))) void*)l, 16, 0, 0);
}

// ---------------- convert x (f32 -> bf16), 4 elems/thread ----------------
__global__ __launch_bounds__(256) void k_cvt_x(const float* __restrict__ x,
                                               ushort_t* __restrict__ xb) {
  int i = blockIdx.x * 256 + threadIdx.x;
  float4v v = ((const float4v*)x)[i];
  ushort4v o;
  o[0] = f2bf(v[0]); o[1] = f2bf(v[1]); o[2] = f2bf(v[2]); o[3] = f2bf(v[3]);
  ((ushort4v*)xb)[i] = o;
}

// ------------- transpose + convert: W[R][C] f32 -> Wt[C][R] bf16 -------------
__global__ __launch_bounds__(256) void k_transpose(const float* __restrict__ W,
                                                   ushort_t* __restrict__ Wt,
                                                   int R, int C) {
  __shared__ ushort_t tile[32][33];
  int tx = threadIdx.x & 31, ty = threadIdx.x >> 5;
  int r0 = blockIdx.y << 5, c0 = blockIdx.x << 5;
#pragma unroll
  for (int i = 0; i < 4; ++i) {
    int r = ty + i * 8;
    tile[r][tx] = f2bf(W[(size_t)(r0 + r) * C + c0 + tx]);
  }
  __syncthreads();
#pragma unroll
  for (int i = 0; i < 4; ++i) {
    int r = ty + i * 8;
    Wt[(size_t)(c0 + r) * R + r0 + tx] = tile[tx][r];
  }
}

// ---------------- GEMM: C[M][N] = A[M][K] * Bt[N][K]^T, bf16 MFMA ----------------
template <int N, int K, int EPI>
__global__ __launch_bounds__(256) void k_gemm(const ushort_t* __restrict__ A,
                                              const ushort_t* __restrict__ Bt,
                                              ushort_t* __restrict__ O16,
                                              float* __restrict__ O32) {
  __shared__ __align__(16) ushort_t Atile[128 * 32];
  __shared__ __align__(16) ushort_t Btile[128 * 32];
  const int tid = threadIdx.x;
  const int lane = tid & 63, w = tid >> 6;
  const int g = lane >> 4, c = lane & 15;
  const int wm = w >> 1, wn = w & 1;
  const int m0 = blockIdx.y * 128, n0 = blockIdx.x * 128;

  f32x4 acc[4][4];
#pragma unroll
  for (int i = 0; i < 4; ++i)
#pragma unroll
    for (int j = 0; j < 4; ++j) acc[i][j] = (f32x4){0.f, 0.f, 0.f, 0.f};

  for (int k0 = 0; k0 < K; k0 += 32) {
    __syncthreads();
#pragma unroll
    for (int r = 0; r < 2; ++r) {
      int flat = r * 256 + tid;
      int row = flat >> 2, slot = flat & 3;
      int gsl = slot ^ (row & 3);                 // source-swizzle (rule #21)
      load_lds16(A + (size_t)(m0 + row) * K + k0 + gsl * 8,
                 &Atile[(r * 256 + w * 64) * 8]);
      load_lds16(Bt + (size_t)(n0 + row) * K + k0 + gsl * 8,
                 &Btile[(r * 256 + w * 64) * 8]);
    }
    __syncthreads();

    bf16x8 af[4], bfr[4];
#pragma unroll
    for (int mi = 0; mi < 4; ++mi) {
      int row = wm * 64 + mi * 16 + c;
      int sl = g ^ (row & 3);
      af[mi] = *(const bf16x8*)&Atile[row * 32 + sl * 8];
    }
#pragma unroll
    for (int ni = 0; ni < 4; ++ni) {
      int row = wn * 64 + ni * 16 + c;
      int sl = g ^ (row & 3);
      bfr[ni] = *(const bf16x8*)&Btile[row * 32 + sl * 8];
    }
#pragma unroll
    for (int mi = 0; mi < 4; ++mi)
#pragma unroll
      for (int ni = 0; ni < 4; ++ni)
        acc[mi][ni] = __builtin_amdgcn_mfma_f32_16x16x32_bf16(af[mi], bfr[ni],
                                                              acc[mi][ni], 0, 0, 0);
  }

#pragma unroll
  for (int mi = 0; mi < 4; ++mi)
#pragma unroll
    for (int ni = 0; ni < 4; ++ni) {
      int n = n0 + wn * 64 + ni * 16 + c;
#pragma unroll
      for (int j = 0; j < 4; ++j) {
        int m = m0 + wm * 64 + mi * 16 + g * 4 + j;
        float v = acc[mi][ni][j];
        if constexpr (EPI == 0) {
          int which = n >> 10, hn = n & 1023;
          int h = hn >> 6, d = hn & 63;
          int b = m >> 11, t = m & 2047;
          if (which == 0) v *= 0.125f;            // fold 1/sqrt(HD) into Q
          O16[(size_t)which * PERQKV +
              (((size_t)(b * NHEAD + h) * T_LEN + t) * HDIM + d)] = f2bf(v);
        } else {
          O32[(size_t)m * N + n] = v;
        }
      }
    }
}

// ---------------- flash attention, paired q-tiles ----------------
// Block p handles q-tile A=31-p then B=p sequentially: exactly 33 compute
// iterations per block (perfect triangular balance). K and V are reg-staged
// (T14: issue loads for tile t+1 before compute(t); ds_write after the
// post-compute barrier), single LDS buffer each.
// Kt: [k][d] with granule swizzle p -> holds d-granule p^(k&7).
// VtT: [d][k] with granule swizzle p -> holds k-granule p^(d&7).
__global__ __launch_bounds__(256) void k_attn(const ushort_t* __restrict__ Q,
                                              const ushort_t* __restrict__ Kv,
                                              const ushort_t* __restrict__ Vv,
                                              ushort_t* __restrict__ Y) {
  __shared__ __align__(16) ushort_t Kt[64 * 64];
  __shared__ __align__(16) ushort_t VtT[64 * 64];
  __shared__ __align__(16) ushort_t Pl[4][16 * 72];

  // XCD grouping: blocks with same (bid&7) share an XCD; give each XCD
  // 8 consecutive bh (K+V for 8 bh = 4MB = one XCD L2).
  const int bid = blockIdx.x;
  const int logical = (bid & 7) * 128 + (bid >> 3);
  const int bh = logical >> 4;
  const int pair = logical & 15;
  const int qtA = 31 - pair, qtB = pair;

  const int tid = threadIdx.x, lane = tid & 63, w = tid >> 6;
  const int g = lane >> 4, c = lane & 15;
  const size_t base = (size_t)bh * (T_LEN * HDIM);

  // staging decomposition
  const int ksl = tid & 7;                 // K: d-granule
  const int krow_st = tid >> 3;            // K: rows krow_st, krow_st+32
  const int kpair = tid & 31;              // V: k-pair -> rows 2kp, 2kp+1
  const int vk0 = 2 * kpair;
  const int vd0 = (tid >> 5) * 8;          // V: d-chunk

  // current-phase state
  int qt = qtA;
  bf16x8 qa[2];
#pragma unroll
  for (int ds = 0; ds < 2; ++ds)
    qa[ds] = *(const bf16x8*)(Q + base + (size_t)(qt * 64 + w * 16 + c) * HDIM + ds * 32 + g * 8);
  f32x4 o[4];
#pragma unroll
  for (int b = 0; b < 4; ++b) o[b] = (f32x4){0.f, 0.f, 0.f, 0.f};
  float mrun[4], lrun[4];
#pragma unroll
  for (int j = 0; j < 4; ++j) { mrun[j] = -__builtin_inff(); lrun[j] = 0.f; }

  const int b_ = bh >> 4, h_ = bh & 15;
  auto epilogue = [&](int qtile) {
#pragma unroll
    for (int bb = 0; bb < 4; ++bb)
#pragma unroll
      for (int j = 0; j < 4; ++j) {
        int qr = qtile * 64 + w * 16 + g * 4 + j;
        float val = o[bb][j] / lrun[j];
        size_t m = (size_t)b_ * T_LEN + qr;
        Y[m * D_DIM + h_ * HDIM + bb * 16 + c] = f2bf(val);
      }
  };

  // staging registers
  bf16x8 kreg[2];
  ushort8v v0r, v1r;
  auto stage_issue = [&](int kt) {
    const ushort_t* kb = Kv + base + (size_t)kt * 64 * HDIM;
    const ushort_t* vb = Vv + base + (size_t)kt * 64 * HDIM;
    v0r = *(const ushort8v*)(vb + (size_t)vk0 * HDIM + vd0);
    v1r = *(const ushort8v*)(vb + (size_t)(vk0 + 1) * HDIM + vd0);
    kreg[0] = *(const bf16x8*)(kb + (size_t)krow_st * HDIM + ksl * 8);
    kreg[1] = *(const bf16x8*)(kb + (size_t)(krow_st + 32) * HDIM + ksl * 8);
  };
  auto stage_write = [&]() {
#pragma unroll
    for (int r = 0; r < 2; ++r) {
      int row = krow_st + r * 32;
      *(bf16x8*)&Kt[row * 64 + ((ksl ^ (row & 7)) << 3)] = kreg[r];
    }
#pragma unroll
    for (int e = 0; e < 8; ++e) {
      int rd = vd0 + e;
      unsigned pv = (unsigned)v0r[e] | ((unsigned)v1r[e] << 16);
      *(unsigned*)&VtT[rd * 64 + ((kpair >> 2) ^ (rd & 7)) * 8 + 2 * (kpair & 3)] = pv;
    }
  };

  // prologue: stage tile 0
  stage_issue(0);
  stage_write();            // compiler inserts the vmcnt waits for reg deps
  __syncthreads();

  const int totalIters = qtA + 1 + qtB + 1;  // 33
  for (int it = 0; it < totalIters; ++it) {
    // phase switch: finish A, start B
    if (it == qtA + 1) {
      epilogue(qtA);
      qt = qtB;
#pragma unroll
      for (int ds = 0; ds < 2; ++ds)
        qa[ds] = *(const bf16x8*)(Q + base + (size_t)(qt * 64 + w * 16 + c) * HDIM + ds * 32 + g * 8);
#pragma unroll
      for (int b = 0; b < 4; ++b) o[b] = (f32x4){0.f, 0.f, 0.f, 0.f};
#pragma unroll
      for (int j = 0; j < 4; ++j) { mrun[j] = -__builtin_inff(); lrun[j] = 0.f; }
    }
    const int kt = (it <= qtA) ? it : it - (qtA + 1);

    // prefetch next tile (possibly phase B's tile 0) before compute
    if (it + 1 < totalIters) {
      int itn = it + 1;
      int ktn = (itn <= qtA) ? itn : itn - (qtA + 1);
      stage_issue(ktn);
    }

    // ----- compute tile kt -----
    f32x4 s[4];
#pragma unroll
    for (int kf = 0; kf < 4; ++kf) {
      f32x4 z = (f32x4){0.f, 0.f, 0.f, 0.f};
#pragma unroll
      for (int ds = 0; ds < 2; ++ds) {
        int krow = kf * 16 + c;
        int sl = (ds * 4 + g) ^ (krow & 7);
        bf16x8 kb = *(const bf16x8*)&Kt[krow * 64 + sl * 8];
        z = __builtin_amdgcn_mfma_f32_16x16x32_bf16(qa[ds], kb, z, 0, 0, 0);
      }
      s[kf] = z;
    }

    const int qr_acc_base = qt * 64 + w * 16 + g * 4;
    if (kt == qt) {  // diagonal causal mask
#pragma unroll
      for (int kf = 0; kf < 4; ++kf)
#pragma unroll
        for (int j = 0; j < 4; ++j) {
          int kc = kt * 64 + kf * 16 + c;
          if (kc > qr_acc_base + j) s[kf][j] = -1e30f;
        }
    }

    float scale_o[4];
#pragma unroll
    for (int j = 0; j < 4; ++j) {
      float mx = fmaxf(fmaxf(s[0][j], s[1][j]), fmaxf(s[2][j], s[3][j]));
      mx = fmaxf(mx, __shfl_xor(mx, 1));
      mx = fmaxf(mx, __shfl_xor(mx, 2));
      mx = fmaxf(mx, __shfl_xor(mx, 4));
      mx = fmaxf(mx, __shfl_xor(mx, 8));
      float mnew = fmaxf(mrun[j], mx);
      float sc = __expf(mrun[j] - mnew);
      float rs = 0.f;
#pragma unroll
      for (int kf = 0; kf < 4; ++kf) {
        float p = __expf(s[kf][j] - mnew);
        s[kf][j] = p; rs += p;
      }
      rs += __shfl_xor(rs, 1); rs += __shfl_xor(rs, 2);
      rs += __shfl_xor(rs, 4); rs += __shfl_xor(rs, 8);
      lrun[j] = lrun[j] * sc + rs;
      mrun[j] = mnew;
      scale_o[j] = sc;
    }
#pragma unroll
    for (int b = 0; b < 4; ++b)
#pragma unroll
      for (int j = 0; j < 4; ++j) o[b][j] *= scale_o[j];

#pragma unroll
    for (int kf = 0; kf < 4; ++kf)
#pragma unroll
      for (int j = 0; j < 4; ++j)
        Pl[w][(g * 4 + j) * 72 + kf * 16 + c] = f2bf(s[kf][j]);

    asm volatile("s_waitcnt lgkmcnt(0)" ::: "memory");

#pragma unroll
    for (int ks = 0; ks < 2; ++ks) {
      bf16x8 ap = *(const bf16x8*)&Pl[w][c * 72 + ks * 32 + g * 8];
#pragma unroll
      for (int b = 0; b < 4; ++b) {
        int sl = (ks * 4 + g) ^ (c & 7);
        bf16x8 vb = *(const bf16x8*)&VtT[(b * 16 + c) * 64 + sl * 8];
        o[b] = __builtin_amdgcn_mfma_f32_16x16x32_bf16(ap, vb, o[b], 0, 0, 0);
      }
    }
    // ----- end compute -----

    __syncthreads();                 // reads done; vmcnt(0) drained here
    if (it + 1 < totalIters) stage_write();
    __syncthreads();
  }

  epilogue(qtB);
}

extern "C" void kernel_launch(void* const* d_in, const int* in_sizes, int n_in,
                              void* d_out, int out_size, void* d_ws, size_t ws_size,
                              hipStream_t stream) {
  const float* x     = (const float*)d_in[0];
  const float* Wqkv  = (const float*)d_in[1];
  const float* Wproj = (const float*)d_in[2];
  float* out = (float*)d_out;
  ushort_t* ws = (ushort_t*)d_ws;

  ushort_t* Xb  = ws;
  ushort_t* WqT = Xb  + (size_t)MROWS * D_DIM;        // 8192*1024
  ushort_t* WpT = WqT + (size_t)3 * D_DIM * D_DIM;    // 3072*1024
  ushort_t* Qb  = WpT + (size_t)D_DIM * D_DIM;        // 1024*1024
  ushort_t* Kb  = Qb + PERQKV;
  ushort_t* Vb  = Kb + PERQKV;
  ushort_t* Yb  = Vb + PERQKV;

  k_cvt_x<<<(MROWS * D_DIM / 4) / 256, 256, 0, stream>>>(x, Xb);
  k_transpose<<<dim3(3 * D_DIM / 32, D_DIM / 32), 256, 0, stream>>>(Wqkv, WqT, D_DIM, 3 * D_DIM);
  k_transpose<<<dim3(D_DIM / 32, D_DIM / 32), 256, 0, stream>>>(Wproj, WpT, D_DIM, D_DIM);
  k_gemm<3 * D_DIM, D_DIM, 0><<<dim3(3 * D_DIM / 128, MROWS / 128), 256, 0, stream>>>(Xb, WqT, Qb, nullptr);
  k_attn<<<1024, 256, 0, stream>>>(Qb, Kb, Vb, Yb);
  k_gemm<D_DIM, D_DIM, 1><<<dim3(D_DIM / 128, MROWS / 128), 256, 0, stream>>>(Yb, WpT, nullptr, out);
}